// Round 8
// baseline (246.889 us; speedup 1.0000x reference)
//
#include <hip/hip_runtime.h>

#define T_LEN  4096
#define KS     16
#define NCHUNK 256      // T_LEN / 16
#define LEAD   6        // consumer lags producers by 6 chunks
#define SLOTS  8        // LDS ring slots
#define BU_PAD 20       // bu row stride in dwords
#define TCOLS  65       // tile row stride: 65 mod 32 = 1 -> conflict-free writes

#define ALPHA_F 0.9048374180359595f
#define BETA_F  0.09516258196404048f
#define THETA_F 0.5f

// Full-wave (64-lane) max, result in ALL lanes. 4 fused DPP max levels, then
// permlane32_swap / permlane16_swap + max. Manual s_nop 1 before every
// DPP/permlane consumer (VALU->DPP needs 2 wait states; compiler can't see
// inside the asm block). Verbatim from the passing R3/R4/R5/R7 kernels.
__device__ __forceinline__ float wave64_max_all(float v) {
  float m, t;
  asm("s_nop 1\n\t"
      "v_max_f32 %0, %2, %2 quad_perm:[1,0,3,2] row_mask:0xf bank_mask:0xf\n\t"
      "s_nop 1\n\t"
      "v_max_f32 %0, %0, %0 quad_perm:[2,3,0,1] row_mask:0xf bank_mask:0xf\n\t"
      "s_nop 1\n\t"
      "v_max_f32 %0, %0, %0 row_half_mirror row_mask:0xf bank_mask:0xf\n\t"
      "s_nop 1\n\t"
      "v_max_f32 %0, %0, %0 row_mirror row_mask:0xf bank_mask:0xf\n\t"
      "v_mov_b32 %1, %0\n\t"
      "s_nop 1\n\t"
      "v_permlane32_swap_b32 %1, %0\n\t"
      "s_nop 1\n\t"
      "v_max_f32 %0, %0, %1\n\t"
      "v_mov_b32 %1, %0\n\t"
      "s_nop 1\n\t"
      "v_permlane16_swap_b32 %1, %0\n\t"
      "s_nop 1\n\t"
      "v_max_f32 %0, %0, %1"
      : "=&v"(m), "=&v"(t)
      : "v"(v));
  return m;
}

__global__ __launch_bounds__(192, 1)
void convlif_wta_kernel(const float* __restrict__ x, const float* __restrict__ W,
                        float* __restrict__ out) {
  const int b    = blockIdx.x;
  const int wave = threadIdx.x >> 6;   // 0,1 = producers(+flush); 2 = consumer
  const int lane = threadIdx.x & 63;   // channel k

  __shared__ float bu_lds[SLOTS][64][BU_PAD];   // 40 KB  (conv ring)
  __shared__ float tile[2][64][TCOLS];          // 32.5 KB (spike tile, dbuf)

  float* outB = out + (size_t)b * 64 * T_LEN;

  if (wave < 2) {
    // ========== producers: causal conv + tile flush (no zero-fill) =========
    float w[KS];
    {
      const float4* w4 = reinterpret_cast<const float4*>(W + lane * KS);
      #pragma unroll
      for (int q = 0; q < 4; ++q) {
        float4 a = w4[q];
        w[4*q+0] = a.x; w[4*q+1] = a.y; w[4*q+2] = a.z; w[4*q+3] = a.w;
      }
    }
    const float4* xv4 = reinterpret_cast<const float4*>(x + (size_t)b * T_LEN);

    for (int s = 0; s < NCHUNK + LEAD + 1; ++s) {
      if (s < NCHUNK && (s & 1) == wave) {
        const int c = s;
        // xf[m] = x[16c-16+m], m = 0..31 (x[<0] treated as 0)
        float xf[32];
        if (c == 0) {
          #pragma unroll
          for (int m = 0; m < 16; ++m) xf[m] = 0.0f;
        } else {
          const int b4 = 4 * c - 4;
          #pragma unroll
          for (int q = 0; q < 4; ++q) {
            float4 a = xv4[b4 + q];
            xf[4*q+0] = a.x; xf[4*q+1] = a.y; xf[4*q+2] = a.z; xf[4*q+3] = a.w;
          }
        }
        #pragma unroll
        for (int q = 0; q < 4; ++q) {
          float4 a = xv4[4*c + q];
          xf[16+4*q+0] = a.x; xf[16+4*q+1] = a.y;
          xf[16+4*q+2] = a.z; xf[16+4*q+3] = a.w;
        }

        // u[t=16c+i] = sum_j w[j]*x[t-15+j]; summation order identical to R7
        float u[16];
        #pragma unroll
        for (int i = 0; i < 16; ++i) {
          float acc = w[0] * xf[1 + i];
          #pragma unroll
          for (int j = 1; j < KS; ++j) acc = fmaf(w[j], xf[1 + i + j], acc);
          u[i] = BETA_F * acc;
        }

        float4* dst = reinterpret_cast<float4*>(&bu_lds[c & (SLOTS-1)][lane][0]);
        dst[0] = make_float4(u[0],  u[1],  u[2],  u[3]);
        dst[1] = make_float4(u[4],  u[5],  u[6],  u[7]);
        dst[2] = make_float4(u[8],  u[9],  u[10], u[11]);
        dst[3] = make_float4(u[12], u[13], u[14], u[15]);
      }

      // flush completed 64-step tile T at s = 4T+10 (consumer finished it at
      // s-1; barrier below orders LDS writes -> these reads). Consumer reuses
      // the buffer starting s = 4T+14 -> no overlap.
      if (s >= 10 && (s & 3) == 2) {
        const int T = (s - 10) >> 2;
        if (T < T_LEN / 64) {
          const int pl   = wave * 64 + lane;   // 0..127
          const int colq = (pl & 15) * 4;      // 0,4,...,60
          const int r0   = pl >> 4;            // 0..7
          const float* tb = &tile[T & 1][0][0];
          #pragma unroll
          for (int it = 0; it < 8; ++it) {
            const int r = r0 + it * 8;
            const float* src = tb + r * TCOLS + colq;   // scalar ds reads, 2-way max
            float4 vq = make_float4(src[0], src[1], src[2], src[3]);
            *reinterpret_cast<float4*>(&outB[(size_t)r * T_LEN + T * 64 + colq]) = vq;
          }
        }
      }
      __syncthreads();
    }
  } else {
    // ================= consumer: serial LIF + WTA recurrence ==============
    float v = 0.0f;
    float4 b0, b1, b2, b3;

    for (int s = 0; s < NCHUNK + LEAD + 1; ++s) {
      if (s == LEAD - 1) {
        // chunk 0 was written at s=0; LEAD-1 barriers have passed -> safe
        const float4* src = reinterpret_cast<const float4*>(&bu_lds[0][lane][0]);
        b0 = src[0]; b1 = src[1]; b2 = src[2]; b3 = src[3];
      } else if (s >= LEAD && s < NCHUNK + LEAD) {
        const int c = s - LEAD;
        float bu[16] = { b0.x, b0.y, b0.z, b0.w,  b1.x, b1.y, b1.z, b1.w,
                         b2.x, b2.y, b2.z, b2.w,  b3.x, b3.y, b3.z, b3.w };

        // per-chunk static tile row base; ds_write offsets are compile-time
        float* trow = &tile[(c >> 2) & 1][lane][(c & 3) * 16];

        #pragma unroll
        for (int i = 0; i < 16; ++i) {
          v = fmaf(ALPHA_F, v, bu[i]);          // same arithmetic as R7
          float vm = v - THETA_F;               // exact; (vm>=0) <=> (v>=theta)
          float sv = 0.0f;

          unsigned long long sp = __ballot(v >= THETA_F);
          if (__builtin_expect(sp != 0ull, 1)) {
            int wl;
            if (__builtin_expect((sp & (sp - 1ull)) != 0ull, 1)) {
              // >=2 candidates: winner = first lane attaining the global max
              float m = wave64_max_all(v);
              unsigned long long eq = __ballot(v == m);
              wl = __builtin_ctzll(eq);
            } else {
              // exactly one lane >= theta: it IS the argmax
              wl = __builtin_ctzll(sp);
            }
            // branchless apply: v_cmp + cndmask, no exec-mask branch
            bool win = (lane == wl);
            sv = win ? 1.0f : 0.0f;
            v  = win ? vm : v;                  // v - s*theta, exact
          }
          trow[i] = sv;                         // conflict-free ds_write
        }

        // prefetch next chunk's bu (produced >= 1 barrier ago; slot safe)
        if (c + 1 < NCHUNK) {
          const float4* src =
              reinterpret_cast<const float4*>(&bu_lds[(c + 1) & (SLOTS-1)][lane][0]);
          b0 = src[0]; b1 = src[1]; b2 = src[2]; b3 = src[3];
        }
      }
      __syncthreads();
    }
  }
}

extern "C" void kernel_launch(void* const* d_in, const int* in_sizes, int n_in,
                              void* d_out, int out_size, void* d_ws, size_t ws_size,
                              hipStream_t stream) {
  const float* x   = (const float*)d_in[0];
  const float* W   = (const float*)d_in[1];
  float*       out = (float*)d_out;
  convlif_wta_kernel<<<dim3(256), dim3(192), 0, stream>>>(x, W, out);
}